// Round 11
// baseline (183.479 us; speedup 1.0000x reference)
//
#include <hip/hip_runtime.h>
#include <stdint.h>

#define TT 4096
#define HIDD 1024

typedef __attribute__((ext_vector_type(4))) float f32x4;
typedef __attribute__((ext_vector_type(16))) float f32x16;
typedef __attribute__((ext_vector_type(8))) short s16x8;

static constexpr float kEps = 1e-6f;
static constexpr float kCsc = 0.125f * 1.44269504088896f;  // scale * log2(e), folded into q

// ---- workspace layout (bytes) ----
static constexpr size_t OFF_HS   = 0;          // bf16 hs swz   [4096][1024]  8 MB
static constexpr size_t OFF_WQKV = 8388608;    // bf16 WqkvT swz [1536][1024] 3 MB
static constexpr size_t OFF_WO   = 11534336;   // bf16 WoT swz  [1024][1024]  2 MB
static constexpr size_t OFF_QKV  = 13631488;   // f32 qkv       [4096][1536] 24 MB
static constexpr size_t OFF_Q    = 0;          // bf16 q  [16][4096][64] (reuse HS)
static constexpr size_t OFF_K    = 8388608;    // bf16 k swz [4][4096][64] (reuse WQKV)
static constexpr size_t OFF_VT   = 38797312;   // bf16 vT swz [4][64][4096] 2 MB
static constexpr size_t OFF_O    = 13631488;   // bf16 attn-out swz [4096][1024] (reuse QKV)

__device__ __forceinline__ unsigned int pk_bf16(float a, float b) {
  union { float f; unsigned int u; } x, y;
  x.f = a; y.f = b;
  unsigned int lo = (x.u + 0x7fffu + ((x.u >> 16) & 1u)) >> 16;
  unsigned int hi = (y.u + 0x7fffu + ((y.u >> 16) & 1u)) >> 16;
  return (lo & 0xffffu) | (hi << 16);
}
__device__ __forceinline__ unsigned short bf16_1(float a) {
  union { float f; unsigned int u; } x; x.f = a;
  return (unsigned short)((x.u + 0x7fffu + ((x.u >> 16) & 1u)) >> 16);
}
__device__ __forceinline__ unsigned int cvtpk(float lo, float hi) {
  unsigned int r;
  asm("v_cvt_pk_bf16_f32 %0, %1, %2" : "=v"(r) : "v"(lo), "v"(hi));
  return r;
}
__device__ __forceinline__ void gload16(const void* g, void* l) {
  __builtin_amdgcn_global_load_lds(
      (const __attribute__((address_space(1))) unsigned int*)g,
      (__attribute__((address_space(3))) unsigned int*)l, 16, 0, 0);
}

// hs fp32 [T][1024] -> bf16 swizzled (16B chunk index XORed by row&7 within 64-elem groups)
__global__ void k_convert_hs(const float* __restrict__ hs, unsigned short* __restrict__ out) {
  int idx = blockIdx.x * 256 + threadIdx.x;  // T*128
  int t = idx >> 7, kc = idx & 127;
  const float4* src = (const float4*)(hs + (size_t)t * HIDD + kc * 8);
  float4 a = src[0], b = src[1];
  int kcs = (kc & ~7) | ((kc & 7) ^ (t & 7));
  uint4 w;
  w.x = pk_bf16(a.x, a.y); w.y = pk_bf16(a.z, a.w);
  w.z = pk_bf16(b.x, b.y); w.w = pk_bf16(b.z, b.w);
  *(uint4*)(out + (size_t)t * HIDD + kcs * 8) = w;
}

// All four weight matrices: fp32 [1024][ncols] -> bf16 W^T [ncols][1024] swizzled by n&7
__global__ void k_convert_w_all(const float* __restrict__ Wq, const float* __restrict__ Wk,
                                const float* __restrict__ Wv, const float* __restrict__ Wo,
                                unsigned short* __restrict__ wqkv, unsigned short* __restrict__ wo_t) {
  int b = blockIdx.x, tid = threadIdx.x;
  const float* W; unsigned short* outT; int nshift, idx;
  if (b < 512)      { W = Wq; outT = wqkv;                nshift = 10; idx = b * 256 + tid; }
  else if (b < 640) { W = Wk; outT = wqkv + 1024 * 1024;  nshift = 8;  idx = (b - 512) * 256 + tid; }
  else if (b < 768) { W = Wv; outT = wqkv + 1280 * 1024;  nshift = 8;  idx = (b - 640) * 256 + tid; }
  else              { W = Wo; outT = wo_t;                nshift = 10; idx = (b - 768) * 256 + tid; }
  int ncols = 1 << nshift;
  int kc = idx >> nshift, n = idx & (ncols - 1);
  float v[8];
#pragma unroll
  for (int e = 0; e < 8; ++e) v[e] = W[(size_t)(kc * 8 + e) * ncols + n];
  int kcs = (kc & ~7) | ((kc & 7) ^ (n & 7));
  uint4 w;
  w.x = pk_bf16(v[0], v[1]); w.y = pk_bf16(v[2], v[3]);
  w.z = pk_bf16(v[4], v[5]); w.w = pk_bf16(v[6], v[7]);
  *(uint4*)(outT + (size_t)n * HIDD + kcs * 8) = w;
}

// C[M][N] = A[M][K] * Bt[N][K]^T ; A,Bt bf16 chunk-swizzled; C fp32.
// 128x64 tile, BK=64, 4 waves (2x2 of 64x32), dbuf LDS (48KB -> 3 blocks/CU).
__global__ __launch_bounds__(256) void k_gemm(const unsigned short* __restrict__ A,
                                              const unsigned short* __restrict__ Bt,
                                              float* __restrict__ C, int M, int N, int K) {
  __shared__ __attribute__((aligned(16))) unsigned short As[2][128 * 64];
  __shared__ __attribute__((aligned(16))) unsigned short Bs[2][64 * 64];
  const int tid = threadIdx.x;
  const int m0 = blockIdx.y * 128, n0 = blockIdx.x * 64;
  const int wid = tid >> 6, lane = tid & 63;
  const int g = lane >> 4, qi = lane & 15;
  const int wr = wid >> 1, wc = wid & 1;
  const int srow = lane >> 3, schk = lane & 7;
  f32x4 acc[4][2] = {};
  const int nkt = K >> 6;

  auto STAGE = [&](int b, int k0) {
#pragma unroll
    for (int j = 0; j < 4; ++j) {
      int ra = j * 32 + wid * 8 + srow;
      gload16(A + (size_t)(m0 + ra) * K + k0 + schk * 8,
              (char*)&As[b][0] + j * 4096 + (wid << 10));
    }
#pragma unroll
    for (int j = 0; j < 2; ++j) {
      int rb = j * 32 + wid * 8 + srow;
      gload16(Bt + (size_t)(n0 + rb) * K + k0 + schk * 8,
              (char*)&Bs[b][0] + j * 4096 + (wid << 10));
    }
  };

  STAGE(0, 0);
  __syncthreads();
  int cur = 0;
  for (int kt = 0; kt < nkt; ++kt) {
    if (kt + 1 < nkt) STAGE(cur ^ 1, (kt + 1) << 6);
#pragma unroll
    for (int kh = 0; kh < 2; ++kh) {
      s16x8 af[4], bq[2];
#pragma unroll
      for (int i = 0; i < 4; ++i) {
        int rA = wr * 64 + i * 16 + qi;
        af[i] = *(const s16x8*)((const char*)&As[cur][0] + rA * 128 + ((((kh << 2) | g) ^ (rA & 7)) << 4));
      }
#pragma unroll
      for (int jn = 0; jn < 2; ++jn) {
        int rB = wc * 32 + jn * 16 + qi;
        bq[jn] = *(const s16x8*)((const char*)&Bs[cur][0] + rB * 128 + ((((kh << 2) | g) ^ (rB & 7)) << 4));
      }
      __builtin_amdgcn_s_setprio(1);
#pragma unroll
      for (int i = 0; i < 4; ++i)
#pragma unroll
        for (int jn = 0; jn < 2; ++jn)
          acc[i][jn] = __builtin_amdgcn_mfma_f32_16x16x32_bf16(af[i], bq[jn], acc[i][jn], 0, 0, 0);
      __builtin_amdgcn_s_setprio(0);
    }
    __syncthreads();
    cur ^= 1;
  }
#pragma unroll
  for (int i = 0; i < 4; ++i)
#pragma unroll
    for (int jn = 0; jn < 2; ++jn) {
      int row = m0 + wr * 64 + i * 16 + g * 4;
      int col = n0 + wc * 32 + jn * 16 + qi;
#pragma unroll
      for (int r = 0; r < 4; ++r)
        C[(size_t)(row + r) * N + col] = acc[i][jn][r];
    }
}

// RMSNorm + RoPE for q (slots 0..15) and k (slots 16..19). One wave per (t,slot).
// q pre-scaled by 0.125*log2(e) so attention scores are directly in exp2 domain.
__global__ void k_prep(const float* __restrict__ qkv, const float* __restrict__ cosb,
                       const float* __restrict__ sinb, const float* __restrict__ qw,
                       const float* __restrict__ kw, unsigned short* __restrict__ qo,
                       unsigned short* __restrict__ ko) {
  int rowid = blockIdx.x * 4 + (threadIdx.x >> 6);
  int lane = threadIdx.x & 63;
  int t = rowid / 20, slot = rowid % 20;
  float x = qkv[(size_t)t * 1536 + slot * 64 + lane];
  float ss = x * x;
#pragma unroll
  for (int off = 32; off; off >>= 1) ss += __shfl_xor(ss, off);
  float n = x * rsqrtf(ss * (1.0f / 64.0f) + kEps);
  n *= (slot < 16) ? qw[lane] : kw[lane];
  float c = cosb[t * 32 + (lane & 31)];
  float s = sinb[t * 32 + (lane & 31)];
  float other = __shfl_xor(n, 32);
  float r = (lane < 32) ? (n * c - other * s) : (other * s + n * c);
  if (slot < 16) {
    unsigned short b = bf16_1(r * kCsc);
    qo[((size_t)slot * TT + t) * 64 + lane] = b;   // linear [h][t][d]
  } else {
    unsigned short b = bf16_1(r);
    int hv = slot - 16;
    int d = (((lane >> 3) ^ (t & 7)) << 3) | (lane & 7);  // swizzle chunks by t&7
    ko[((size_t)hv * TT + t) * 64 + d] = b;
  }
}

// v: qkv fp32 [t][1280+hv*64+d] -> bf16 vT [hv][d][t], t-chunks swizzled by d&7
__global__ void k_vT(const float* __restrict__ qkv, unsigned short* __restrict__ vt) {
  __shared__ float tile[64][65];
  int t0 = blockIdx.x * 64, hv = blockIdx.y, tid = threadIdx.x;
  int cc = tid & 63, rr0 = tid >> 6;
#pragma unroll
  for (int i = 0; i < 16; ++i) {
    int r = rr0 * 16 + i;
    tile[r][cc] = qkv[(size_t)(t0 + r) * 1536 + 1280 + hv * 64 + cc];
  }
  __syncthreads();
#pragma unroll
  for (int jj = 0; jj < 2; ++jj) {
    int idx = jj * 256 + tid;
    int d = idx >> 3, tc = idx & 7;
    uint4 w;
    w.x = pk_bf16(tile[tc * 8 + 0][d], tile[tc * 8 + 1][d]);
    w.y = pk_bf16(tile[tc * 8 + 2][d], tile[tc * 8 + 3][d]);
    w.z = pk_bf16(tile[tc * 8 + 4][d], tile[tc * 8 + 5][d]);
    w.w = pk_bf16(tile[tc * 8 + 6][d], tile[tc * 8 + 7][d]);
    int tcs = tc ^ (d & 7);
    *(uint4*)(vt + ((size_t)hv * 64 + d) * TT + t0 + tcs * 8) = w;
  }
}

// Flash attention, causal GQA — 32q/wave, 32x32x16 MFMA, in-register P via
// v_permlane32_swap (R10 math, verified) + R5's proven packing: 512 blocks x 4 waves;
// block = tile pair (i0, 63-i0) of one head. Waves 0,1 = units of tile i0
// (extent i0+1), waves 2,3 = units of tile 63-i0 (extent E=64-i0, block loop len).
// All waves share one staged K/V dbuf stream (both tiles read kv tile st at step st).
// Block lengths E in [33,64]; i0 mirrored at t>=32 so breadth-first placement gives
// constant 97-step per-CU work. LDS 56KB -> exactly 2 blocks/CU (8 waves/CU).
__global__ __launch_bounds__(256, 2) void k_attn(const unsigned short* __restrict__ q,
                                                 const unsigned short* __restrict__ kk,
                                                 const unsigned short* __restrict__ vt,
                                                 unsigned short* __restrict__ o) {
  __shared__ __attribute__((aligned(16))) char smem[57344];  // K dbuf 16K @0, V dbuf 16K @16384, pad
  const int tid = threadIdx.x;
  const int wid = tid >> 6, lane = tid & 63;
  const int ln31 = lane & 31, hi = lane >> 5;
  const int bid = blockIdx.x;
  const int xcd = bid & 7;
  const int t = bid >> 3;                       // [0,64) within XCD
  const int head = xcd * 2 + (t >> 5);          // 2 heads per XCD (one KV group L2-resident)
  const int i0 = (t < 32) ? t : (63 - t);       // mirrored: t and t+32 have complementary E
  const int hv = head >> 2;
  const int unit = (wid < 2) ? (2 * i0 + wid) : (126 - 2 * i0 + (wid - 2));
  const int qbase = unit * 32;                  // this wave's 32 q-rows
  const int e_w = (unit >> 1) + 1;              // this wave's kv steps
  const int E = 64 - i0;                        // block staging extent

  auto STAGE = [&](int b, int st) {
    const int kv0 = st * 64;
#pragma unroll
    for (int p = 0; p < 2; ++p) {
      int c = tid + p * 256;
      int row = c >> 3, ch = c & 7;
      gload16(kk + ((size_t)hv * TT + kv0 + row) * 64 + ch * 8,
              smem + b * 8192 + c * 16);
      gload16(vt + ((size_t)hv * 64 + row) * TT + kv0 + ch * 8,
              smem + 16384 + b * 8192 + c * 16);
    }
  };

  // Q fragments (B-operand): lane holds Q[qbase+ln31, d = ks*16 + hi*8 + j]
  s16x8 qf[4];
#pragma unroll
  for (int ks = 0; ks < 4; ++ks)
    qf[ks] = *(const s16x8*)(q + ((size_t)head * TT + qbase + ln31) * 64 + ks * 16 + hi * 8);

  f32x16 oacc[2] = {};
  float lp0 = 0.0f, lp1 = 0.0f;

  STAGE(0, 0);
  __syncthreads();
  int cur = 0;
  for (int st = 0; st < E; ++st) {
    if (st + 1 < E) STAGE(cur ^ 1, st + 1);
    if (st < e_w) {
      const int kv0 = st * 64;
      const char* Kb = smem + cur * 8192;
      const char* Vb = smem + 16384 + cur * 8192;
      // QK^T: C[kv][q] (2 kv-tiles of 32), A = K, B = Q
      f32x16 sacc[2] = {};
#pragma unroll
      for (int T = 0; T < 2; ++T) {
#pragma unroll
        for (int ks = 0; ks < 4; ++ks) {
          int row = T * 32 + ln31;
          s16x8 kf = *(const s16x8*)(Kb + row * 128 + (((2 * ks + hi) ^ (row & 7)) << 4));
          sacc[T] = __builtin_amdgcn_mfma_f32_32x32x16_bf16(kf, qf[ks], sacc[T], 0, 0, 0);
        }
      }
      // softmax (fixed max, exp2 domain; per-lane q = qbase+ln31)
      float pv[32];
      const bool diag = (st == e_w - 1);
      const int qg = qbase + ln31;
#pragma unroll
      for (int T = 0; T < 2; ++T)
#pragma unroll
        for (int r = 0; r < 16; ++r) {
          float v = sacc[T][r];
          if (diag) {
            int kvg = kv0 + T * 32 + (r & 3) + 8 * (r >> 2) + 4 * hi;
            if (kvg > qg) v = -1e30f;
          }
          float e = exp2f(v);
          pv[T * 16 + r] = e;
          if (r & 1) lp1 += e; else lp0 += e;
        }
      // pack P to bf16 A-fragments via permlane32_swap (no LDS)
      s16x8 pa[4];
#pragma unroll
      for (int ks = 0; ks < 4; ++ks) {
        const float* pg = pv + ks * 8;
        unsigned w0 = cvtpk(pg[0], pg[1]);
        unsigned w1 = cvtpk(pg[2], pg[3]);
        unsigned w2 = cvtpk(pg[4], pg[5]);
        unsigned w3 = cvtpk(pg[6], pg[7]);
        asm("v_permlane32_swap_b32 %0, %1" : "+v"(w0), "+v"(w2));
        asm("v_permlane32_swap_b32 %0, %1" : "+v"(w1), "+v"(w3));
        union { uint4 u4; s16x8 v8; } cc;
        cc.u4.x = w0; cc.u4.y = w1; cc.u4.z = w2; cc.u4.w = w3;
        pa[ks] = cc.v8;
      }
      // PV: C[q][d] (2 d-tiles of 32), A = P, B = V (from vT tile rows = d)
#pragma unroll
      for (int D = 0; D < 2; ++D) {
#pragma unroll
        for (int ks = 0; ks < 4; ++ks) {
          int row = D * 32 + ln31;
          s16x8 vf = *(const s16x8*)(Vb + row * 128 + (((2 * ks + hi) ^ (row & 7)) << 4));
          oacc[D] = __builtin_amdgcn_mfma_f32_32x32x16_bf16(pa[ks], vf, oacc[D], 0, 0, 0);
        }
      }
    }
    __syncthreads();
    cur ^= 1;
  }
  // normalize + store: lane ln31 holds l for q = qbase+ln31 (after cross-hi add)
  float lfull = lp0 + lp1;
  lfull += __shfl_xor(lfull, 32);
  float invl = 1.0f / lfull;
#pragma unroll
  for (int r = 0; r < 16; ++r) {
    int qoff = (r & 3) + 8 * (r >> 2) + 4 * hi;
    float il = __shfl(invl, qoff);
    int q_g = qbase + qoff;
    size_t rowb = (size_t)q_g * 2048 + head * 128 + (lane & 7) * 2;
#pragma unroll
    for (int D = 0; D < 2; ++D) {
      int ch = ((4 * D + (ln31 >> 3)) ^ (q_g & 7)) << 4;
      *(unsigned short*)((char*)o + rowb + ch) = bf16_1(oacc[D][r] * il);
    }
  }
}

extern "C" void kernel_launch(void* const* d_in, const int* in_sizes, int n_in,
                              void* d_out, int out_size, void* d_ws, size_t ws_size,
                              hipStream_t stream) {
  const float* hs   = (const float*)d_in[0];
  const float* cosb = (const float*)d_in[1];
  const float* sinb = (const float*)d_in[2];
  const float* Wq   = (const float*)d_in[3];
  const float* Wk   = (const float*)d_in[4];
  const float* Wv   = (const float*)d_in[5];
  const float* Wo   = (const float*)d_in[6];
  const float* qw   = (const float*)d_in[7];
  const float* kw   = (const float*)d_in[8];
  char* ws = (char*)d_ws;
  unsigned short* hs_swz = (unsigned short*)(ws + OFF_HS);
  unsigned short* wqkv   = (unsigned short*)(ws + OFF_WQKV);
  unsigned short* wo_t   = (unsigned short*)(ws + OFF_WO);
  float*          qkv    = (float*)(ws + OFF_QKV);
  unsigned short* qbf    = (unsigned short*)(ws + OFF_Q);
  unsigned short* kbf    = (unsigned short*)(ws + OFF_K);
  unsigned short* vtb    = (unsigned short*)(ws + OFF_VT);
  unsigned short* obf    = (unsigned short*)(ws + OFF_O);

  k_convert_hs<<<2048, 256, 0, stream>>>(hs, hs_swz);
  k_convert_w_all<<<1280, 256, 0, stream>>>(Wq, Wk, Wv, Wo, wqkv, wo_t);
  k_gemm<<<dim3(24, 32), 256, 0, stream>>>(hs_swz, wqkv, qkv, 4096, 1536, 1024);
  k_prep<<<20480, 256, 0, stream>>>(qkv, cosb, sinb, qw, kw, qbf, kbf);
  k_vT<<<dim3(64, 4), 256, 0, stream>>>(qkv, vtb);
  k_attn<<<512, 256, 0, stream>>>(qbf, kbf, vtb, obf);
  k_gemm<<<dim3(16, 32), 256, 0, stream>>>(obf, wo_t, (float*)d_out, 4096, 1024, 1024);
}

// Round 12
// 131.146 us; speedup vs baseline: 1.3990x; 1.3990x over previous
//
#include <hip/hip_runtime.h>
#include <stdint.h>

#define TT 4096
#define HIDD 1024

typedef __attribute__((ext_vector_type(4))) float f32x4;
typedef __attribute__((ext_vector_type(8))) short s16x8;

static constexpr float kEps = 1e-6f;
static constexpr float kCsc = 0.125f * 1.44269504088896f;  // scale * log2(e), folded into q

// ---- workspace layout (bytes) ----
static constexpr size_t OFF_HS   = 0;          // bf16 hs swz   [4096][1024]  8 MB
static constexpr size_t OFF_WQKV = 8388608;    // bf16 WqkvT swz [1536][1024] 3 MB
static constexpr size_t OFF_WO   = 11534336;   // bf16 WoT swz  [1024][1024]  2 MB
static constexpr size_t OFF_Q    = 13631488;   // bf16 q  [16][4096][64]  8 MB
static constexpr size_t OFF_K    = 22020096;   // bf16 k swz [4][4096][64] 2 MB
static constexpr size_t OFF_O    = 24117248;   // bf16 attn-out swz [4096][1024] 8 MB
static constexpr size_t OFF_VT   = 38797312;   // bf16 vT swz [4][64][4096] 2 MB

__device__ __forceinline__ unsigned int pk_bf16(float a, float b) {
  union { float f; unsigned int u; } x, y;
  x.f = a; y.f = b;
  unsigned int lo = (x.u + 0x7fffu + ((x.u >> 16) & 1u)) >> 16;
  unsigned int hi = (y.u + 0x7fffu + ((y.u >> 16) & 1u)) >> 16;
  return (lo & 0xffffu) | (hi << 16);
}
__device__ __forceinline__ unsigned int cvtpk(float lo, float hi) {
  unsigned int r;
  asm("v_cvt_pk_bf16_f32 %0, %1, %2" : "=v"(r) : "v"(lo), "v"(hi));
  return r;
}
__device__ __forceinline__ void gload16(const void* g, void* l) {
  __builtin_amdgcn_global_load_lds(
      (const __attribute__((address_space(1))) unsigned int*)g,
      (__attribute__((address_space(3))) unsigned int*)l, 16, 0, 0);
}

// hs fp32 [T][1024] -> bf16 swizzled (16B chunk index XORed by row&7 within 64-elem groups)
__global__ void k_convert_hs(const float* __restrict__ hs, unsigned short* __restrict__ out) {
  int idx = blockIdx.x * 256 + threadIdx.x;  // T*128
  int t = idx >> 7, kc = idx & 127;
  const float4* src = (const float4*)(hs + (size_t)t * HIDD + kc * 8);
  float4 a = src[0], b = src[1];
  int kcs = (kc & ~7) | ((kc & 7) ^ (t & 7));
  uint4 w;
  w.x = pk_bf16(a.x, a.y); w.y = pk_bf16(a.z, a.w);
  w.z = pk_bf16(b.x, b.y); w.w = pk_bf16(b.z, b.w);
  *(uint4*)(out + (size_t)t * HIDD + kcs * 8) = w;
}

// All four weight matrices: fp32 [1024][ncols] -> bf16 W^T [ncols][1024] swizzled by n&7
__global__ void k_convert_w_all(const float* __restrict__ Wq, const float* __restrict__ Wk,
                                const float* __restrict__ Wv, const float* __restrict__ Wo,
                                unsigned short* __restrict__ wqkv, unsigned short* __restrict__ wo_t) {
  int b = blockIdx.x, tid = threadIdx.x;
  const float* W; unsigned short* outT; int nshift, idx;
  if (b < 512)      { W = Wq; outT = wqkv;                nshift = 10; idx = b * 256 + tid; }
  else if (b < 640) { W = Wk; outT = wqkv + 1024 * 1024;  nshift = 8;  idx = (b - 512) * 256 + tid; }
  else if (b < 768) { W = Wv; outT = wqkv + 1280 * 1024;  nshift = 8;  idx = (b - 640) * 256 + tid; }
  else              { W = Wo; outT = wo_t;                nshift = 10; idx = (b - 768) * 256 + tid; }
  int ncols = 1 << nshift;
  int kc = idx >> nshift, n = idx & (ncols - 1);
  float v[8];
#pragma unroll
  for (int e = 0; e < 8; ++e) v[e] = W[(size_t)(kc * 8 + e) * ncols + n];
  int kcs = (kc & ~7) | ((kc & 7) ^ (n & 7));
  uint4 w;
  w.x = pk_bf16(v[0], v[1]); w.y = pk_bf16(v[2], v[3]);
  w.z = pk_bf16(v[4], v[5]); w.w = pk_bf16(v[6], v[7]);
  *(uint4*)(outT + (size_t)n * HIDD + kcs * 8) = w;
}

// Fused QKV GEMM + RMSNorm + RoPE + bf16 layout conversion.
// C-tile = 128 rows x 64 cols, and 64 cols == exactly one head slot (N=1536, 24 slots:
// 16 q, 4 k, 4 v). After the K-loop the f32 tile goes to LDS; epilogue applies
// RMSNorm+RoPE (q,k) or transpose (v) and stores bf16 in the attention layouts.
__global__ __launch_bounds__(256) void k_gemm_qkv(const unsigned short* __restrict__ A,
                                                  const unsigned short* __restrict__ Bt,
                                                  const float* __restrict__ cosb,
                                                  const float* __restrict__ sinb,
                                                  const float* __restrict__ qw,
                                                  const float* __restrict__ kw,
                                                  unsigned short* __restrict__ qo,
                                                  unsigned short* __restrict__ ko,
                                                  unsigned short* __restrict__ vt) {
  __shared__ __attribute__((aligned(16))) char smem[49152];  // staging 48KB / C f32 128x66 33KB
  const int K = HIDD;
  const int tid = threadIdx.x;
  const int m0 = blockIdx.y * 128, slot = blockIdx.x, n0 = slot * 64;
  const int wid = tid >> 6, lane = tid & 63;
  const int g = lane >> 4, qi = lane & 15;
  const int wr = wid >> 1, wc = wid & 1;
  const int srow = lane >> 3, schk = lane & 7;
  f32x4 acc[4][2] = {};
  const int nkt = K >> 6;

  auto STAGE = [&](int b, int k0) {
#pragma unroll
    for (int j = 0; j < 4; ++j) {
      int ra = j * 32 + wid * 8 + srow;
      gload16(A + (size_t)(m0 + ra) * K + k0 + schk * 8,
              smem + b * 16384 + j * 4096 + (wid << 10));
    }
#pragma unroll
    for (int j = 0; j < 2; ++j) {
      int rb = j * 32 + wid * 8 + srow;
      gload16(Bt + (size_t)(n0 + rb) * K + k0 + schk * 8,
              smem + 32768 + b * 8192 + j * 4096 + (wid << 10));
    }
  };

  STAGE(0, 0);
  __syncthreads();
  int cur = 0;
  for (int kt = 0; kt < nkt; ++kt) {
    if (kt + 1 < nkt) STAGE(cur ^ 1, (kt + 1) << 6);
#pragma unroll
    for (int kh = 0; kh < 2; ++kh) {
      s16x8 af[4], bq[2];
#pragma unroll
      for (int i = 0; i < 4; ++i) {
        int rA = wr * 64 + i * 16 + qi;
        af[i] = *(const s16x8*)(smem + cur * 16384 + rA * 128 + ((((kh << 2) | g) ^ (rA & 7)) << 4));
      }
#pragma unroll
      for (int jn = 0; jn < 2; ++jn) {
        int rB = wc * 32 + jn * 16 + qi;
        bq[jn] = *(const s16x8*)(smem + 32768 + cur * 8192 + rB * 128 + ((((kh << 2) | g) ^ (rB & 7)) << 4));
      }
      __builtin_amdgcn_s_setprio(1);
#pragma unroll
      for (int i = 0; i < 4; ++i)
#pragma unroll
        for (int jn = 0; jn < 2; ++jn)
          acc[i][jn] = __builtin_amdgcn_mfma_f32_16x16x32_bf16(af[i], bq[jn], acc[i][jn], 0, 0, 0);
      __builtin_amdgcn_s_setprio(0);
    }
    __syncthreads();
    cur ^= 1;
  }

  // ---- epilogue ----
  float* Cs = (float*)smem;                 // [128][66] f32
#pragma unroll
  for (int i = 0; i < 4; ++i)
#pragma unroll
    for (int jn = 0; jn < 2; ++jn) {
      int row = wr * 64 + i * 16 + g * 4;
      int col = wc * 32 + jn * 16 + qi;
#pragma unroll
      for (int r = 0; r < 4; ++r)
        Cs[(row + r) * 66 + col] = acc[i][jn][r];
    }
  __syncthreads();

  if (slot < 20) {
    // q/k: RMSNorm + RoPE. 2 threads per row (halves of 32).
    const int lr = tid >> 1, hf = tid & 1;
    const int t = m0 + lr;
    const float* self_p = Cs + lr * 66 + hf * 32;
    const float* oth_p  = Cs + lr * 66 + (1 - hf) * 32;
    float ss = 0.0f;
#pragma unroll
    for (int e = 0; e < 32; ++e) { float v = self_p[e]; ss += v * v; }
    ss += __shfl_xor(ss, 1);
    const float rms = rsqrtf(ss * (1.0f / 64.0f) + kEps);
    const float* wvec = (slot < 16) ? qw : kw;
    const float outscale = (slot < 16) ? kCsc : 1.0f;
    unsigned int u[16];
#pragma unroll
    for (int ee = 0; ee < 16; ++ee) {
      float o2[2];
#pragma unroll
      for (int p = 0; p < 2; ++p) {
        int e = 2 * ee + p;
        float c = cosb[t * 32 + e];
        float s = sinb[t * 32 + e];
        float self = self_p[e] * rms * wvec[hf * 32 + e];
        float oth  = oth_p[e]  * rms * wvec[(1 - hf) * 32 + e];
        float r = hf ? (oth * s + self * c) : (self * c - oth * s);
        o2[p] = r * outscale;
      }
      u[ee] = cvtpk(o2[0], o2[1]);
    }
    if (slot < 16) {
      unsigned short* base = qo + ((size_t)slot * TT + t) * 64 + hf * 32;
#pragma unroll
      for (int cidx = 0; cidx < 4; ++cidx) {
        uint4 w; w.x = u[cidx * 4]; w.y = u[cidx * 4 + 1]; w.z = u[cidx * 4 + 2]; w.w = u[cidx * 4 + 3];
        *(uint4*)(base + cidx * 8) = w;
      }
    } else {
      const int hv = slot - 16;
      unsigned short* base = ko + ((size_t)hv * TT + t) * 64;
#pragma unroll
      for (int cidx = 0; cidx < 4; ++cidx) {
        int gc = hf * 4 + cidx;
        uint4 w; w.x = u[cidx * 4]; w.y = u[cidx * 4 + 1]; w.z = u[cidx * 4 + 2]; w.w = u[cidx * 4 + 3];
        *(uint4*)(base + (gc ^ (t & 7)) * 8) = w;
      }
    }
  } else {
    // v: transpose to vT [hv][d][t] with t-chunk swizzle by d&7
    const int hv = slot - 20;
#pragma unroll
    for (int tt = 0; tt < 2; ++tt)
#pragma unroll
      for (int jj = 0; jj < 2; ++jj) {
        int idx = jj * 256 + tid;
        int d = idx >> 3, tc = idx & 7;
        uint4 w;
        w.x = cvtpk(Cs[(tt * 64 + tc * 8 + 0) * 66 + d], Cs[(tt * 64 + tc * 8 + 1) * 66 + d]);
        w.y = cvtpk(Cs[(tt * 64 + tc * 8 + 2) * 66 + d], Cs[(tt * 64 + tc * 8 + 3) * 66 + d]);
        w.z = cvtpk(Cs[(tt * 64 + tc * 8 + 4) * 66 + d], Cs[(tt * 64 + tc * 8 + 5) * 66 + d]);
        w.w = cvtpk(Cs[(tt * 64 + tc * 8 + 6) * 66 + d], Cs[(tt * 64 + tc * 8 + 7) * 66 + d]);
        int tcs = tc ^ (d & 7);
        *(uint4*)(vt + ((size_t)hv * 64 + d) * TT + m0 + tt * 64 + tcs * 8) = w;
      }
  }
}

// C[M][N] = A[M][K] * Bt[N][K]^T ; 128x64 tile, BK=64, 4 waves, dbuf LDS (output proj).
__global__ __launch_bounds__(256) void k_gemm(const unsigned short* __restrict__ A,
                                              const unsigned short* __restrict__ Bt,
                                              float* __restrict__ C, int M, int N, int K) {
  __shared__ __attribute__((aligned(16))) unsigned short As[2][128 * 64];
  __shared__ __attribute__((aligned(16))) unsigned short Bs[2][64 * 64];
  const int tid = threadIdx.x;
  const int m0 = blockIdx.y * 128, n0 = blockIdx.x * 64;
  const int wid = tid >> 6, lane = tid & 63;
  const int g = lane >> 4, qi = lane & 15;
  const int wr = wid >> 1, wc = wid & 1;
  const int srow = lane >> 3, schk = lane & 7;
  f32x4 acc[4][2] = {};
  const int nkt = K >> 6;

  auto STAGE = [&](int b, int k0) {
#pragma unroll
    for (int j = 0; j < 4; ++j) {
      int ra = j * 32 + wid * 8 + srow;
      gload16(A + (size_t)(m0 + ra) * K + k0 + schk * 8,
              (char*)&As[b][0] + j * 4096 + (wid << 10));
    }
#pragma unroll
    for (int j = 0; j < 2; ++j) {
      int rb = j * 32 + wid * 8 + srow;
      gload16(Bt + (size_t)(n0 + rb) * K + k0 + schk * 8,
              (char*)&Bs[b][0] + j * 4096 + (wid << 10));
    }
  };

  STAGE(0, 0);
  __syncthreads();
  int cur = 0;
  for (int kt = 0; kt < nkt; ++kt) {
    if (kt + 1 < nkt) STAGE(cur ^ 1, (kt + 1) << 6);
#pragma unroll
    for (int kh = 0; kh < 2; ++kh) {
      s16x8 af[4], bq[2];
#pragma unroll
      for (int i = 0; i < 4; ++i) {
        int rA = wr * 64 + i * 16 + qi;
        af[i] = *(const s16x8*)((const char*)&As[cur][0] + rA * 128 + ((((kh << 2) | g) ^ (rA & 7)) << 4));
      }
#pragma unroll
      for (int jn = 0; jn < 2; ++jn) {
        int rB = wc * 32 + jn * 16 + qi;
        bq[jn] = *(const s16x8*)((const char*)&Bs[cur][0] + rB * 128 + ((((kh << 2) | g) ^ (rB & 7)) << 4));
      }
      __builtin_amdgcn_s_setprio(1);
#pragma unroll
      for (int i = 0; i < 4; ++i)
#pragma unroll
        for (int jn = 0; jn < 2; ++jn)
          acc[i][jn] = __builtin_amdgcn_mfma_f32_16x16x32_bf16(af[i], bq[jn], acc[i][jn], 0, 0, 0);
      __builtin_amdgcn_s_setprio(0);
    }
    __syncthreads();
    cur ^= 1;
  }
#pragma unroll
  for (int i = 0; i < 4; ++i)
#pragma unroll
    for (int jn = 0; jn < 2; ++jn) {
      int row = m0 + wr * 64 + i * 16 + g * 4;
      int col = n0 + wc * 32 + jn * 16 + qi;
#pragma unroll
      for (int r = 0; r < 4; ++r)
        C[(size_t)(row + r) * N + col] = acc[i][jn][r];
    }
}

// Flash attention, causal GQA — the R5/R9 best-measured configuration (78.6us).
// 512 threads = 8 waves: waves 0-3 own q-tile i0, waves 4-7 own q-tile 63-i0; both
// share the same K/V double-buffered staging. FIXED-MAX exp2 softmax (RMSNorm bounds
// |q.k*scale*log2e| <= 11.6 -> P = exp2(s) directly); normalize by l at the end.
// LDS padded to 56KB so exactly 2 blocks/CU -> even packing of 512 uniform blocks.
__global__ __launch_bounds__(512) void k_attn(const unsigned short* __restrict__ q,
                                              const unsigned short* __restrict__ kk,
                                              const unsigned short* __restrict__ vt,
                                              unsigned short* __restrict__ o) {
  __shared__ __attribute__((aligned(16))) unsigned short Kl[2][64 * 64];
  __shared__ __attribute__((aligned(16))) unsigned short Vl[2][64 * 64];
  __shared__ __attribute__((aligned(16))) unsigned short Pl[8][1536];  // 1024 used + pad -> 56KB total
  const int tid = threadIdx.x;
  const int bid = blockIdx.x;
  const int work = (bid & 7) * 64 + (bid >> 3);    // XCD-chunked: 2 heads per XCD
  const int h = work >> 5;
  const int i0 = work & 31;
  const int hv = h >> 2;
  const int wid = tid >> 6, lane = tid & 63, g = lane >> 4, qi = lane & 15;
  const int qt = (wid < 4) ? i0 : (63 - i0);       // per-wave q-tile
  const int smax = 63 - i0;
  char* pb = (char*)&Pl[wid][0];

  auto STAGE = [&](int b, int s) {
    const int kv0 = s * 64;
    const int r = wid * 8 + (lane >> 3), c8 = (lane & 7) * 8;
    gload16(kk + ((size_t)hv * TT + kv0 + r) * 64 + c8, (char*)&Kl[b][0] + (wid << 10));
    gload16(vt + ((size_t)hv * 64 + r) * TT + kv0 + c8, (char*)&Vl[b][0] + (wid << 10));
  };

  const int qg = qt * 64 + (wid & 3) * 16 + qi;
  s16x8 qf[2];
#pragma unroll
  for (int kh = 0; kh < 2; ++kh)
    qf[kh] = *(const s16x8*)(q + ((size_t)h * TT + qg) * 64 + kh * 32 + g * 8);
  f32x4 acc[4] = {};
  float l0 = 0.0f, l1 = 0.0f;

  STAGE(0, 0);
  __syncthreads();
  int cur = 0;
  for (int s = 0; s <= smax; ++s) {
    if (s < smax) STAGE(cur ^ 1, s + 1);
    if (s <= qt) {
      const int kv0 = s * 64;
      f32x4 sacc[4] = {};
#pragma unroll
      for (int kh = 0; kh < 2; ++kh) {
        s16x8 kf[4];
#pragma unroll
        for (int cf = 0; cf < 4; ++cf) {
          int row = cf * 16 + qi;
          kf[cf] = *(const s16x8*)((const char*)&Kl[cur][0] + row * 128 + ((((kh << 2) | g) ^ (row & 7)) << 4));
        }
        __builtin_amdgcn_s_setprio(1);
#pragma unroll
        for (int cf = 0; cf < 4; ++cf)
          sacc[cf] = __builtin_amdgcn_mfma_f32_16x16x32_bf16(kf[cf], qf[kh], sacc[cf], 0, 0, 0);
        __builtin_amdgcn_s_setprio(0);
      }
      float pv[16];
      if (s == qt) {
#pragma unroll
        for (int cf = 0; cf < 4; ++cf)
#pragma unroll
          for (int r = 0; r < 4; ++r) {
            float v = sacc[cf][r];
            if ((kv0 + cf * 16 + g * 4 + r) > qg) v = -1e30f;
            pv[cf * 4 + r] = v;
          }
      } else {
#pragma unroll
        for (int cf = 0; cf < 4; ++cf)
#pragma unroll
          for (int r = 0; r < 4; ++r) pv[cf * 4 + r] = sacc[cf][r];
      }
#pragma unroll
      for (int i = 0; i < 8; ++i) {
        float e0 = exp2f(pv[2 * i]), e1 = exp2f(pv[2 * i + 1]);
        pv[2 * i] = e0; pv[2 * i + 1] = e1;
        l0 += e0; l1 += e1;
      }
#pragma unroll
      for (int cf = 0; cf < 4; ++cf) {
        int chunk = cf * 2 + (g >> 1);
        int base = qi * 128 + ((chunk ^ (qi & 7)) << 4) + ((g & 1) << 3);
        uint2 pw;
        pw.x = cvtpk(pv[cf * 4 + 0], pv[cf * 4 + 1]);
        pw.y = cvtpk(pv[cf * 4 + 2], pv[cf * 4 + 3]);
        *(uint2*)(pb + base) = pw;
      }
#pragma unroll
      for (int kh = 0; kh < 2; ++kh) {
        s16x8 pf = *(const s16x8*)(pb + qi * 128 + ((((kh << 2) | g) ^ (qi & 7)) << 4));
        s16x8 vf[4];
#pragma unroll
        for (int cf = 0; cf < 4; ++cf) {
          int row = cf * 16 + qi;
          vf[cf] = *(const s16x8*)((const char*)&Vl[cur][0] + row * 128 + ((((kh << 2) | g) ^ (row & 7)) << 4));
        }
        __builtin_amdgcn_s_setprio(1);
#pragma unroll
        for (int cf = 0; cf < 4; ++cf)
          acc[cf] = __builtin_amdgcn_mfma_f32_16x16x32_bf16(vf[cf], pf, acc[cf], 0, 0, 0);
        __builtin_amdgcn_s_setprio(0);
      }
    }
    __syncthreads();
    cur ^= 1;
  }
  float l_run = l0 + l1;
  l_run += __shfl_xor(l_run, 16);
  l_run += __shfl_xor(l_run, 32);
  float inv = 1.0f / l_run;
#pragma unroll
  for (int cf = 0; cf < 4; ++cf) {
    int col = h * 64 + cf * 16 + g * 4;
    int chunk = col >> 3;
    int chs = (chunk & ~7) | ((chunk & 7) ^ (qg & 7));
    char* ob = (char*)o + (size_t)qg * 2048 + (chs << 4) + ((g & 1) << 3);
    *(unsigned int*)ob = cvtpk(acc[cf][0] * inv, acc[cf][1] * inv);
    *(unsigned int*)(ob + 4) = cvtpk(acc[cf][2] * inv, acc[cf][3] * inv);
  }
}

extern "C" void kernel_launch(void* const* d_in, const int* in_sizes, int n_in,
                              void* d_out, int out_size, void* d_ws, size_t ws_size,
                              hipStream_t stream) {
  const float* hs   = (const float*)d_in[0];
  const float* cosb = (const float*)d_in[1];
  const float* sinb = (const float*)d_in[2];
  const float* Wq   = (const float*)d_in[3];
  const float* Wk   = (const float*)d_in[4];
  const float* Wv   = (const float*)d_in[5];
  const float* Wo   = (const float*)d_in[6];
  const float* qw   = (const float*)d_in[7];
  const float* kw   = (const float*)d_in[8];
  char* ws = (char*)d_ws;
  unsigned short* hs_swz = (unsigned short*)(ws + OFF_HS);
  unsigned short* wqkv   = (unsigned short*)(ws + OFF_WQKV);
  unsigned short* wo_t   = (unsigned short*)(ws + OFF_WO);
  unsigned short* qbf    = (unsigned short*)(ws + OFF_Q);
  unsigned short* kbf    = (unsigned short*)(ws + OFF_K);
  unsigned short* vtb    = (unsigned short*)(ws + OFF_VT);
  unsigned short* obf    = (unsigned short*)(ws + OFF_O);

  k_convert_hs<<<2048, 256, 0, stream>>>(hs, hs_swz);
  k_convert_w_all<<<1280, 256, 0, stream>>>(Wq, Wk, Wv, Wo, wqkv, wo_t);
  k_gemm_qkv<<<dim3(24, 32), 256, 0, stream>>>(hs_swz, wqkv, cosb, sinb, qw, kw, qbf, kbf, vtb);
  k_attn<<<512, 512, 0, stream>>>(qbf, kbf, vtb, obf);
  k_gemm<<<dim3(16, 32), 256, 0, stream>>>(obf, wo_t, (float*)d_out, 4096, 1024, 1024);
}